// Round 7
// baseline (186.816 us; speedup 1.0000x reference)
//
#include <hip/hip_runtime.h>
#include <hip/hip_fp16.h>

#define CCH 48         // channels
#define NPB 128        // nodes per bucket (1<<7); requires N <= 128*1024
#define NPB_SH 7
#define MAXNB 1024     // max buckets (scan width)
#define EPT 12         // edges per thread in scatter
#define SCAT_THR 512
#define SCAT_EPB (SCAT_THR * EPT)  // 6144
#define SRCL 3072      // per-bucket sorted src list bound (mean 2046, ~22 sigma)

// --- k1: LDS counting-sort scatter, 512 thr, shuffle scans ---
// col record: row | (col&127)<<24 (4B) -> pairs[]   row record: row&127 (1B) -> rbytes[]
__global__ void __launch_bounds__(SCAT_THR) bucket_scatter(
    const int* __restrict__ row, const int* __restrict__ col,
    int* __restrict__ colCur, int* __restrict__ rowCur,
    int* __restrict__ pairs, unsigned char* __restrict__ rbytes,
    int NB, int E, int CAPC, int CAPR) {
    __shared__ int cnt[MAXNB];     // counts, then cursors
    __shared__ int start[MAXNB];   // block-local exclusive prefix
    __shared__ int gbase[MAXNB];   // global fragment base
    __shared__ int wsum[8];
    __shared__ int srec[SCAT_EPB];             // 24KB sort buffer (int/byte view)
    __shared__ unsigned short skey[SCAT_EPB];  // 12KB bucket key by sorted pos
    int tid = threadIdx.x;
    int lane = tid & 63, w6 = tid >> 6;
    int base = blockIdx.x * SCAT_EPB;
    int c[EPT], r[EPT];
    bool full = (base + SCAT_EPB <= E);
    if (full) {
#pragma unroll
        for (int k = 0; k < EPT / 4; ++k) {
            int idx = base + (k * SCAT_THR + tid) * 4;
            *reinterpret_cast<int4*>(&c[k * 4]) = *reinterpret_cast<const int4*>(col + idx);
            *reinterpret_cast<int4*>(&r[k * 4]) = *reinterpret_cast<const int4*>(row + idx);
        }
    } else {
#pragma unroll
        for (int k = 0; k < EPT; ++k) {
            int e = base + k * SCAT_THR + tid;
            if (e < E) { c[k] = col[e]; r[k] = row[e]; } else { c[k] = -1; r[k] = 0; }
        }
    }
    int total = 0;
    // ================= two phases: 0 = col (pairs), 1 = row (rbytes) =================
    for (int ph = 0; ph < 2; ++ph) {
        for (int i = tid; i < MAXNB; i += SCAT_THR) cnt[i] = 0;
        __syncthreads();
#pragma unroll
        for (int k = 0; k < EPT; ++k)
            if (full || c[k] >= 0)
                atomicAdd(&cnt[(ph ? r[k] : c[k]) >> NPB_SH], 1);
        __syncthreads();
        // scan 1024 buckets: 2/thread + wave-shuffle inclusive scan over 512
        int c0 = cnt[2 * tid], c1 = cnt[2 * tid + 1];
        int sum2 = c0 + c1;
        int inc = sum2;
#pragma unroll
        for (int off = 1; off < 64; off <<= 1) {
            int u = __shfl_up(inc, off);
            if (lane >= off) inc += u;
        }
        if (lane == 63) wsum[w6] = inc;
        __syncthreads();
        if (w6 == 0) {
            int w = (lane < 8) ? wsum[lane] : 0;
#pragma unroll
            for (int off = 1; off < 8; off <<= 1) {
                int u = __shfl_up(w, off);
                if (lane >= off) w += u;
            }
            if (lane < 8) wsum[lane] = w;
        }
        __syncthreads();
        int incl = inc + (w6 ? wsum[w6 - 1] : 0);
        start[2 * tid] = incl - sum2;
        start[2 * tid + 1] = incl - c1;
        if (ph == 0) total = wsum[7];
        __syncthreads();
        // reserve line-padded global fragments; cnt[] becomes local cursor
        if (ph == 0) {
            for (int i = tid; i < NB; i += SCAT_THR) {
                int nc = cnt[i];
                if (nc) {
                    int padded = (nc + 15) & ~15;
                    int b0 = i * CAPC + atomicAdd(colCur + i, padded);
                    gbase[i] = b0;
                    for (int j = nc; j < padded; ++j) pairs[b0 + j] = -1;
                }
                cnt[i] = start[i];
            }
        } else {
            for (int i = tid; i < NB; i += SCAT_THR) {
                int nr = cnt[i];
                if (nr) {
                    int padded = (nr + 31) & ~31;  // 32B sector multiple
                    int b0 = i * CAPR + atomicAdd(rowCur + i, padded);
                    gbase[i] = b0;
                    for (int j = nr; j < padded; ++j) rbytes[b0 + j] = 0xFF;
                }
                cnt[i] = start[i];
            }
        }
        __syncthreads();
        // sorted placement into LDS
        if (ph == 0) {
#pragma unroll
            for (int k = 0; k < EPT; ++k)
                if (full || c[k] >= 0) {
                    int b = c[k] >> NPB_SH;
                    int p = atomicAdd(&cnt[b], 1);
                    srec[p] = r[k] | ((c[k] & (NPB - 1)) << 24);
                    skey[p] = (unsigned short)b;
                }
        } else {
            unsigned char* sbyte = reinterpret_cast<unsigned char*>(srec);
#pragma unroll
            for (int k = 0; k < EPT; ++k)
                if (full || c[k] >= 0) {
                    int b = r[k] >> NPB_SH;
                    int p = atomicAdd(&cnt[b], 1);
                    sbyte[p] = (unsigned char)(r[k] & (NPB - 1));
                    skey[p] = (unsigned short)b;
                }
        }
        __syncthreads();
        // coalesced burst write-out
        if (ph == 0) {
            for (int i = tid; i < total; i += SCAT_THR) {
                int b = skey[i];
                pairs[gbase[b] + (i - start[b])] = srec[i];
            }
        } else {
            const unsigned char* sbyte = reinterpret_cast<const unsigned char*>(srec);
            for (int i = tid; i < total; i += SCAT_THR) {
                int b = skey[i];
                rbytes[gbase[b] + (i - start[b])] = sbyte[i];
            }
        }
        __syncthreads();
    }
}

// --- k2: per-bucket row-degree histogram -> dis + fused fp16 scale-convert ---
__global__ void __launch_bounds__(256) deg_conv(const unsigned char* __restrict__ rbytes,
                                                const int* __restrict__ rowCur,
                                                const float* __restrict__ label,
                                                float* __restrict__ dis,
                                                __half* __restrict__ lab16,
                                                int N, int CAPR) {
    __shared__ int cnt[256];  // slot 255 catches 0xFF sentinels
    __shared__ float ds[NPB];
    int b = blockIdx.x, tid = threadIdx.x;
    cnt[tid] = 0;
    __syncthreads();
    int begr = b * CAPR;
    int rnum = rowCur[b];  // padded (multiple of 32)
    int nq4 = rnum >> 2;   // exact
    for (int q = tid; q < nq4; q += 256) {
        uchar4 u = *reinterpret_cast<const uchar4*>(rbytes + begr + q * 4);
        atomicAdd(&cnt[u.x], 1);
        atomicAdd(&cnt[u.y], 1);
        atomicAdd(&cnt[u.z], 1);
        atomicAdd(&cnt[u.w], 1);
    }
    __syncthreads();
    int n0 = b << NPB_SH;
    if (tid < NPB) {
        float w = rsqrtf((float)cnt[tid] + 1.0f);
        ds[tid] = w;
        if (n0 + tid < N) dis[n0 + tid] = w;
    }
    __syncthreads();
    int rr = tid >> 1, hf = tid & 1;
    int n = n0 + rr;
    if (n < N) {
        float w = ds[rr];
        const float4* src4 = reinterpret_cast<const float4*>(label + (size_t)n * CCH + hf * 24);
        uint4* dst = reinterpret_cast<uint4*>(lab16 + (size_t)n * CCH + hf * 24);
#pragma unroll
        for (int k = 0; k < 3; ++k) {
            float4 a = src4[2 * k];
            float4 cc = src4[2 * k + 1];
            union { __half2 h[4]; uint4 u; } pkk;
            pkk.h[0] = __floats2half2_rn(w * a.x, w * a.y);
            pkk.h[1] = __floats2half2_rn(w * a.z, w * a.w);
            pkk.h[2] = __floats2half2_rn(w * cc.x, w * cc.y);
            pkk.h[3] = __floats2half2_rn(w * cc.z, w * cc.w);
            dst[k] = pkk.u;
        }
    }
}

// --- k3: fused CSR-build + pull-gather, one 1024-thr block per bucket ---
// pass1: histogram bucket pairs; shuffle-scan 128 node counts;
// pass2: re-read pairs (L2-hot), place src ids into sorted LDS srcL;
// pass3: 8 lanes/node gather lab16 rows, self term, write out.
__global__ void __launch_bounds__(1024) csr_gather(const int* __restrict__ pairs,
                                                   const int* __restrict__ colCur,
                                                   const __half* __restrict__ lab16,
                                                   const float* __restrict__ dis,
                                                   float* __restrict__ out,
                                                   int N, int CAPC) {
    __shared__ int srcL[SRCL];  // 12KB sorted src ids
    __shared__ int cnt[NPB], nbeg[NPB], nend[NPB];
    __shared__ int wsum2[2];
    int b = blockIdx.x, tid = threadIdx.x;
    if (tid < NPB) cnt[tid] = 0;
    __syncthreads();
    int begc = b * CAPC;
    int cnum = colCur[b];  // padded (multiple of 16)
    int nq = cnum >> 2;    // exact
    for (int q = tid; q < nq; q += 1024) {
        int4 pk = *reinterpret_cast<const int4*>(pairs + begc + q * 4);
        if (pk.x >= 0) atomicAdd(&cnt[((unsigned)pk.x) >> 24], 1);
        if (pk.y >= 0) atomicAdd(&cnt[((unsigned)pk.y) >> 24], 1);
        if (pk.z >= 0) atomicAdd(&cnt[((unsigned)pk.z) >> 24], 1);
        if (pk.w >= 0) atomicAdd(&cnt[((unsigned)pk.w) >> 24], 1);
    }
    __syncthreads();
    // shuffle-scan of 128 counts (threads 0..127 = waves 0,1)
    int lane = tid & 63, w6 = tid >> 6;
    int v = (tid < NPB) ? cnt[tid] : 0;
    int inc = v;
#pragma unroll
    for (int off = 1; off < 64; off <<= 1) {
        int u = __shfl_up(inc, off);
        if (lane >= off) inc += u;
    }
    if (tid < NPB && lane == 63) wsum2[w6] = inc;
    __syncthreads();
    if (tid < NPB) {
        int incl = inc + ((w6 == 1) ? wsum2[0] : 0);
        nbeg[tid] = incl - v;
        nend[tid] = incl;
        cnt[tid] = incl - v;  // cursor
    }
    __syncthreads();
    // place pass (re-read, L2-hot)
    for (int q = tid; q < nq; q += 1024) {
        int4 pk = *reinterpret_cast<const int4*>(pairs + begc + q * 4);
        if (pk.x >= 0) { int p = atomicAdd(&cnt[((unsigned)pk.x) >> 24], 1); srcL[p] = pk.x & 0x00FFFFFF; }
        if (pk.y >= 0) { int p = atomicAdd(&cnt[((unsigned)pk.y) >> 24], 1); srcL[p] = pk.y & 0x00FFFFFF; }
        if (pk.z >= 0) { int p = atomicAdd(&cnt[((unsigned)pk.z) >> 24], 1); srcL[p] = pk.z & 0x00FFFFFF; }
        if (pk.w >= 0) { int p = atomicAdd(&cnt[((unsigned)pk.w) >> 24], 1); srcL[p] = pk.w & 0x00FFFFFF; }
    }
    __syncthreads();
    // gather: 8 lanes per node, 6 channels per lane
    int nl = tid >> 3;
    int n = (b << NPB_SH) + nl;
    if (n >= N) return;
    int c0 = (tid & 7) * 6;
    float a0 = 0.f, a1 = 0.f, a2 = 0.f, a3 = 0.f, a4 = 0.f, a5 = 0.f;
    int i = nbeg[nl], end = nend[nl];
    for (; i + 4 <= end; i += 4) {
        int s0 = srcL[i], s1 = srcL[i + 1], s2 = srcL[i + 2], s3 = srcL[i + 3];
        const __half2* p0 = reinterpret_cast<const __half2*>(lab16 + (size_t)s0 * CCH + c0);
        const __half2* p1 = reinterpret_cast<const __half2*>(lab16 + (size_t)s1 * CCH + c0);
        const __half2* p2 = reinterpret_cast<const __half2*>(lab16 + (size_t)s2 * CCH + c0);
        const __half2* p3 = reinterpret_cast<const __half2*>(lab16 + (size_t)s3 * CCH + c0);
        __half2 x0 = p0[0], x1 = p0[1], x2 = p0[2];
        __half2 y0 = p1[0], y1 = p1[1], y2 = p1[2];
        __half2 z0 = p2[0], z1 = p2[1], z2 = p2[2];
        __half2 w0 = p3[0], w1 = p3[1], w2 = p3[2];
        float2 f;
        f = __half22float2(x0); a0 += f.x; a1 += f.y;
        f = __half22float2(x1); a2 += f.x; a3 += f.y;
        f = __half22float2(x2); a4 += f.x; a5 += f.y;
        f = __half22float2(y0); a0 += f.x; a1 += f.y;
        f = __half22float2(y1); a2 += f.x; a3 += f.y;
        f = __half22float2(y2); a4 += f.x; a5 += f.y;
        f = __half22float2(z0); a0 += f.x; a1 += f.y;
        f = __half22float2(z1); a2 += f.x; a3 += f.y;
        f = __half22float2(z2); a4 += f.x; a5 += f.y;
        f = __half22float2(w0); a0 += f.x; a1 += f.y;
        f = __half22float2(w1); a2 += f.x; a3 += f.y;
        f = __half22float2(w2); a4 += f.x; a5 += f.y;
    }
    for (; i < end; ++i) {
        int s0 = srcL[i];
        const __half2* p0 = reinterpret_cast<const __half2*>(lab16 + (size_t)s0 * CCH + c0);
        __half2 x0 = p0[0], x1 = p0[1], x2 = p0[2];
        float2 f;
        f = __half22float2(x0); a0 += f.x; a1 += f.y;
        f = __half22float2(x1); a2 += f.x; a3 += f.y;
        f = __half22float2(x2); a4 += f.x; a5 += f.y;
    }
    // self loop: lab16[n] is already dis[n]*label[n]
    {
        const __half2* ps = reinterpret_cast<const __half2*>(lab16 + (size_t)n * CCH + c0);
        __half2 x0 = ps[0], x1 = ps[1], x2 = ps[2];
        float2 f;
        f = __half22float2(x0); a0 += f.x; a1 += f.y;
        f = __half22float2(x1); a2 += f.x; a3 += f.y;
        f = __half22float2(x2); a4 += f.x; a5 += f.y;
    }
    float dn = dis[n];
    float* o = out + (size_t)n * CCH + c0;
    o[0] = dn * a0; o[1] = dn * a1; o[2] = dn * a2;
    o[3] = dn * a3; o[4] = dn * a4; o[5] = dn * a5;
}

extern "C" void kernel_launch(void* const* d_in, const int* in_sizes, int n_in,
                              void* d_out, int out_size, void* d_ws, size_t ws_size,
                              hipStream_t stream) {
    const float* label = (const float*)d_in[0];  // fp32 (N,48)
    const int* ei = (const int*)d_in[1];         // int32, (2,E) flat

    const int NC = in_sizes[0];  // N * 48
    const int N  = NC / CCH;
    const int E  = in_sizes[1] / 2;
    const int* row = ei;
    const int* col = ei + E;

    const int NB = (N + NPB - 1) >> NPB_SH;             // 782 at N=100000
    const int sblocks = (E + SCAT_EPB - 1) / SCAT_EPB;  // 261 at E=1.6M
    const int avg = (E + NB - 1) / NB;                  // ~2047
    const int CAPC = (avg + (avg >> 2) + 15 * sblocks + 15) & ~15;   // ints
    const int CAPR = (avg + (avg >> 2) + 31 * sblocks + 63) & ~63;   // bytes

    // ws layout:
    // [pairs NB*CAPC int] [colCur NB][rowCur NB] [dis N f32] [pad]
    // [rbytes NB*CAPR bytes] [lab16 N*48 half]
    int* pairs = (int*)d_ws;
    int* colCur = pairs + (size_t)NB * CAPC;
    int* rowCur = colCur + NB;
    float* dis = (float*)(rowCur + NB);
    size_t rb_off = (((size_t)(dis + N) - (size_t)d_ws) + 63) & ~(size_t)63;
    unsigned char* rbytes = (unsigned char*)d_ws + rb_off;
    __half* lab16 = (__half*)(rbytes + (size_t)NB * CAPR);

    // zero the two cursor arrays (~6 KB)
    hipMemsetAsync(colCur, 0, (size_t)(2 * NB) * sizeof(int), stream);

    bucket_scatter<<<sblocks, SCAT_THR, 0, stream>>>(row, col, colCur, rowCur,
                                                     pairs, rbytes, NB, E, CAPC, CAPR);
    deg_conv<<<NB, 256, 0, stream>>>(rbytes, rowCur, label, dis, lab16, N, CAPR);
    csr_gather<<<NB, 1024, 0, stream>>>(pairs, colCur, lab16, dis,
                                        (float*)d_out, N, CAPC);
}